// Round 3
// baseline (2777.752 us; speedup 1.0000x reference)
//
#include <hip/hip_runtime.h>
#include <hip/hip_bf16.h>

#define NTOK 1024
#define NB   64
#define CD   256
#define NHEAD 8
#define HDIM 32
#define NS 256      // 16*16 reduced tokens
#define NBC  16384  // NB*CD
#define LPAD 33     // LDS row stride (32 + 1 pad) -> conflict-free row reads

// Cooperatively stage a 256-row x 32-col fp32 tile into LDS (row stride LPAD).
// Global: row r at g + r*rowstride, 32 contiguous floats. Coalesced float4 loads:
// 8 consecutive threads cover one row (8x16B = 128B contiguous segment).
__device__ __forceinline__ void stage_w(const float* __restrict__ g, int rowstride,
                                        float* __restrict__ ls, int t){
  #pragma unroll
  for (int i=0;i<8;++i){
    int j = i*256 + t;               // 0..2047 float4s
    int r = j >> 3, c4 = (j & 7) << 2;
    float4 v = *(const float4*)(g + r*rowstride + c4);
    float* d = ls + r*LPAD + c4;     // 132B row stride -> b32 writes, ~2 lanes/bank
    d[0]=v.x; d[1]=v.y; d[2]=v.z; d[3]=v.w;
  }
}

// ---- trig tables: t1[1024][4] (cos a, sin a, cos b, sin b), t2[256][4] ----
__global__ __launch_bounds__(256) void k_trig(float* __restrict__ t1, float* __restrict__ t2){
  int n = blockIdx.x*256 + threadIdx.x;
  const float c = 1.57079632679489662f;
  float aa = c * (float)(n >> 5) / 32.0f;
  float bb = c * (float)(n & 31) / 32.0f;
  t1[n*4+0]=cosf(aa); t1[n*4+1]=sinf(aa); t1[n*4+2]=cosf(bb); t1[n*4+3]=sinf(bb);
  if (n < 256){
    float a2 = c * (float)(n >> 4) / 16.0f;
    float b2 = c * (float)(n & 15) / 16.0f;
    t2[n*4+0]=cosf(a2); t2[n*4+1]=sinf(a2); t2[n*4+2]=cosf(b2); t2[n*4+3]=sinf(b2);
  }
}

// ---- SE: partial mean over n (4 quarters per b) ----
__global__ __launch_bounds__(256) void k_semean(const float* __restrict__ q, float* __restrict__ part){
  int b = blockIdx.x >> 2, qr = blockIdx.x & 3;
  int c = threadIdx.x;
  const float* qp = q + (qr*256)*NBC + b*CD + c;
  float s0=0.f,s1=0.f,s2=0.f,s3=0.f;
  for (int n=0;n<256;n+=4){
    s0 += qp[(n  )*NBC];
    s1 += qp[(n+1)*NBC];
    s2 += qp[(n+2)*NBC];
    s3 += qp[(n+3)*NBC];
  }
  part[blockIdx.x*256 + c] = (s0+s1)+(s2+s3);
}

// ---- SE MLP: se = sigmoid(relu(mean @ w1^T) @ w2^T), per b ----
__global__ __launch_bounds__(256) void k_semlp(const float* __restrict__ part, const float* __restrict__ w1,
                                               const float* __restrict__ w2, float* __restrict__ se){
  __shared__ float sm[256];
  __shared__ float s1s[128];
  int b = blockIdx.x, t = threadIdx.x;
  float s = (part[(b*4+0)*256+t]+part[(b*4+1)*256+t])+(part[(b*4+2)*256+t]+part[(b*4+3)*256+t]);
  sm[t] = s*(1.0f/1024.0f);
  __syncthreads();
  if (t < 128){
    float a = 0.f;
    const float* wr = w1 + t*256;
    for (int c=0;c<256;c+=4){
      float4 wf = *(const float4*)(wr+c);
      a += sm[c]*wf.x + sm[c+1]*wf.y + sm[c+2]*wf.z + sm[c+3]*wf.w;
    }
    s1s[t] = fmaxf(a, 0.f);
  }
  __syncthreads();
  float a = 0.f;
  const float* wr2 = w2 + t*128;
  for (int c=0;c<128;c+=4){
    float4 wf = *(const float4*)(wr2+c);
    a += s1s[c]*wf.x + s1s[c+1]*wf.y + s1s[c+2]*wf.z + s1s[c+3]*wf.w;
  }
  se[b*256+t] = 1.0f/(1.0f+expf(-a));
}

// ---- conv 2x2 stride 2 as GEMM: xr[b*256 + pos][o], 32 positions/block ----
// sr_w layout: [o][cin][kh][kw] (256,256,2,2); chunk = 8 cins (32 floats/row)
__global__ __launch_bounds__(256) void k_conv(const float* __restrict__ xf, const float* __restrict__ srw,
                                              const float* __restrict__ srb, float* __restrict__ xr){
  __shared__ float ls[256*LPAD];
  int b   = blockIdx.x >> 3;       // 512 blocks
  int hs2 = blockIdx.x & 7;        // 2 hs rows per block
  int o   = threadIdx.x;
  float acc[32];
  #pragma unroll
  for (int m=0;m<32;++m) acc[m]=0.f;
  const float* xb = xf + b*CD;
  for (int ch=0; ch<32; ++ch){
    stage_w(srw + ch*32, 1024, ls, o);
    __syncthreads();
    float wf[32];
    const float* wr = ls + o*LPAD;
    #pragma unroll
    for (int i=0;i<32;++i) wf[i] = wr[i];
    #pragma unroll
    for (int m=0;m<32;++m){
      int hs = hs2*2 + (m>>4);
      int ws = m & 15;
      #pragma unroll
      for (int r=0;r<2;++r){
        #pragma unroll
        for (int kw=0;kw<2;++kw){
          const float* xrow = xb + ((2*hs+r)*32 + 2*ws + kw)*NBC + ch*8;  // wave-uniform
          #pragma unroll
          for (int ci=0;ci<8;++ci) acc[m] += xrow[ci]*wf[ci*4 + r*2 + kw];
        }
      }
    }
    __syncthreads();
  }
  float bias = srb[o];
  int row0 = b*NS + hs2*32;
  #pragma unroll
  for (int m=0;m<32;++m) xr[(row0+m)*CD + o] = acc[m] + bias;
}

// ---- layernorm over C, in place; 4 rows per block (1 per wave) ----
__global__ __launch_bounds__(256) void k_ln(float* __restrict__ xr, const float* __restrict__ g,
                                            const float* __restrict__ bta){
  int wv = threadIdx.x >> 6, lane = threadIdx.x & 63;
  int row = blockIdx.x*4 + wv;
  float4 v = ((const float4*)(xr + row*CD))[lane];
  float s = (v.x+v.y)+(v.z+v.w);
  #pragma unroll
  for (int off=1; off<64; off<<=1) s += __shfl_xor(s, off, 64);
  float mu = s * (1.0f/256.0f);
  float dx=v.x-mu, dy=v.y-mu, dz=v.z-mu, dw=v.w-mu;
  float s2 = (dx*dx+dy*dy)+(dz*dz+dw*dw);
  #pragma unroll
  for (int off=1; off<64; off<<=1) s2 += __shfl_xor(s2, off, 64);
  float inv = 1.0f / sqrtf(s2*(1.0f/256.0f) + 1e-5f);
  float4 gr = ((const float4*)g)[lane];
  float4 br = ((const float4*)bta)[lane];
  float4 o;
  o.x = dx*inv*gr.x + br.x;
  o.y = dy*inv*gr.y + br.y;
  o.z = dz*inv*gr.z + br.z;
  o.w = dw*inv*gr.w + br.w;
  ((float4*)(xr + row*CD))[lane] = o;
}

// ---- Q proj: q = relu(x @ Wq^T + bq) * scaling ; qb[b*1024+n][c], 32 rows/block ----
__global__ __launch_bounds__(256) void k_qproj(const float* __restrict__ xf, const float* __restrict__ ipw,
                                               const float* __restrict__ ipb, float* __restrict__ qb){
  __shared__ float ls[256*LPAD];
  int b  = blockIdx.x >> 5;        // 2048 blocks
  int n0 = (blockIdx.x & 31)*32;
  int o  = threadIdx.x;
  float acc[32];
  #pragma unroll
  for (int m=0;m<32;++m) acc[m]=0.f;
  const float* xb = xf + b*CD;
  for (int ch=0; ch<8; ++ch){
    int cc = ch*32;
    stage_w(ipw + cc, 256, ls, o);
    __syncthreads();
    float wf[32];
    const float* wr = ls + o*LPAD;
    #pragma unroll
    for (int i=0;i<32;++i) wf[i] = wr[i];
    #pragma unroll
    for (int m=0;m<32;++m){
      const float* xrow = xb + (n0+m)*NBC + cc;    // wave-uniform
      #pragma unroll
      for (int i=0;i<32;++i) acc[m] += xrow[i]*wf[i];
    }
    __syncthreads();
  }
  float bq = ipb[o];
  const float sc = 0.17677669529663687f;           // 32^-0.5
  #pragma unroll
  for (int m=0;m<32;++m)
    qb[(b*NTOK + n0 + m)*CD + o] = fmaxf(acc[m]+bq, 0.f)*sc;
}

// ---- K/V proj from xr_ln: k = relu(.+bk), v = .+bv ; 32 rows/block ----
__global__ __launch_bounds__(256) void k_kvproj(const float* __restrict__ xr, const float* __restrict__ ipw,
                                                const float* __restrict__ ipb, float* __restrict__ kb,
                                                float* __restrict__ vbuf){
  __shared__ float ls[256*LPAD];
  int row0 = blockIdx.x*32;        // 512 blocks
  int o = threadIdx.x;
  float ak[32], av[32];
  #pragma unroll
  for (int m=0;m<32;++m){ ak[m]=0.f; av[m]=0.f; }
  for (int ch=0; ch<8; ++ch){
    int cc = ch*32;
    // K tile
    stage_w(ipw + 65536 + cc, 256, ls, o);
    __syncthreads();
    {
      float wf[32];
      const float* wr = ls + o*LPAD;
      #pragma unroll
      for (int i=0;i<32;++i) wf[i] = wr[i];
      #pragma unroll
      for (int m=0;m<32;++m){
        const float* xrow = xr + (row0+m)*CD + cc; // wave-uniform
        #pragma unroll
        for (int i=0;i<32;++i) ak[m] += xrow[i]*wf[i];
      }
    }
    __syncthreads();
    // V tile
    stage_w(ipw + 131072 + cc, 256, ls, o);
    __syncthreads();
    {
      float wf[32];
      const float* wr = ls + o*LPAD;
      #pragma unroll
      for (int i=0;i<32;++i) wf[i] = wr[i];
      #pragma unroll
      for (int m=0;m<32;++m){
        const float* xrow = xr + (row0+m)*CD + cc; // wave-uniform
        #pragma unroll
        for (int i=0;i<32;++i) av[m] += xrow[i]*wf[i];
      }
    }
    __syncthreads();
  }
  float bk = ipb[CD+o];
  float bv = ipb[2*CD+o];
  #pragma unroll
  for (int m=0;m<32;++m){
    kb[(row0+m)*CD+o]   = fmaxf(ak[m]+bk, 0.f);
    vbuf[(row0+m)*CD+o] = av[m]+bv;
  }
}

// ---- kv[bh][d=32p+j][m] = sum_n t2_p(n) k[n,j] v[n,m]; ksum[bh][d] ----
__global__ __launch_bounds__(256) void k_kv(const float* __restrict__ kb, const float* __restrict__ vbuf,
                                            const float* __restrict__ t2, float* __restrict__ kv,
                                            float* __restrict__ ksm){
  int bh = blockIdx.x; int b = bh >> 3, h = bh & 7;
  int t = threadIdx.x; int jq = t >> 5, m = t & 31;
  float acc[4][4];
  #pragma unroll
  for (int p=0;p<4;++p){ acc[p][0]=0.f; acc[p][1]=0.f; acc[p][2]=0.f; acc[p][3]=0.f; }
  const float* kbase = kb + h*HDIM + jq*4;
  const float* vbase = vbuf + h*HDIM + m;
  for (int n=0;n<256;++n){
    int ro = (b*NS + n)*CD;
    float4 k4 = *(const float4*)(kbase + ro);
    float vv = vbase[ro];
    float4 tt = *(const float4*)(t2 + n*4);
    float tv[4] = {tt.x, tt.y, tt.z, tt.w};
    float kk[4] = {k4.x, k4.y, k4.z, k4.w};
    #pragma unroll
    for (int p=0;p<4;++p){
      float tp = tv[p]*vv;
      #pragma unroll
      for (int jj=0;jj<4;++jj) acc[p][jj] += tp*kk[jj];
    }
  }
  #pragma unroll
  for (int p=0;p<4;++p){
    #pragma unroll
    for (int jj=0;jj<4;++jj)
      kv[bh*4096 + (p*32 + jq*4 + jj)*32 + m] = acc[p][jj];
  }
  if (t < 128){
    int p = t >> 5, j = t & 31;
    float s=0.f;
    const float* kp = kb + h*HDIM + j;
    for (int n=0;n<256;++n) s += t2[n*4+p]*kp[(b*NS+n)*CD];
    ksm[bh*128 + t] = s;
  }
}

// ---- attn: per (b,h), per n: acc[m] = sum_d q_[n,d] kv[d][m]; /= clamp(denom) ----
// Q rows staged through LDS (coalesced), kv rows wave-uniform scalar.
__global__ __launch_bounds__(256) void k_attn(const float* __restrict__ qb, const float* __restrict__ kv,
                                              const float* __restrict__ ksm, const float* __restrict__ t1,
                                              float* __restrict__ at){
  __shared__ float ls[256*LPAD];
  int bh = blockIdx.x; int b = bh>>3, h = bh&7;
  const float* kvb = kv + bh*4096;
  const float* ksb = ksm + bh*128;
  for (int u=0;u<4;++u){
    stage_w(qb + (b*NTOK + u*256)*CD + h*HDIM, 256, ls, threadIdx.x);
    __syncthreads();
    int n = u*256 + threadIdx.x;
    float qf[32];
    const float* qr = ls + threadIdx.x*LPAD;
    #pragma unroll
    for (int i=0;i<32;++i) qf[i] = qr[i];
    float4 tt = *(const float4*)(t1 + n*4);
    float tv[4] = {tt.x,tt.y,tt.z,tt.w};
    float acc[32];
    #pragma unroll
    for (int mm=0;mm<32;++mm) acc[mm]=0.f;
    float den = 0.f;
    #pragma unroll
    for (int p=0;p<4;++p){
      float tp = tv[p];
      for (int j=0;j<32;++j){
        float qq = tp*qf[j];
        const float* kvr = kvb + (p*32+j)*32;      // wave-uniform
        #pragma unroll
        for (int mm=0;mm<32;++mm) acc[mm] += qq*kvr[mm];
        den += qq*ksb[p*32+j];
      }
    }
    float sgn = (den>0.f) ? 1.f : ((den<0.f)? -1.f : 0.f);
    float ad = fminf(fmaxf(fabsf(den), 1e-4f), 1e4f);
    float inv = (den != 0.f) ? 1.0f/(ad*sgn) : 0.f;
    float* outb = at + (b*NTOK + n)*CD + h*HDIM;
    #pragma unroll
    for (int mq=0;mq<8;++mq){
      float4 o4 = make_float4(acc[mq*4]*inv, acc[mq*4+1]*inv, acc[mq*4+2]*inv, acc[mq*4+3]*inv);
      ((float4*)outb)[mq] = o4;
    }
    __syncthreads();
  }
}

// ---- out proj + SE scale + transpose to (N,B,C) fp32 ; 32 rows/block ----
__global__ __launch_bounds__(256) void k_outproj(const float* __restrict__ at, const float* __restrict__ ow,
                                                 const float* __restrict__ obv, const float* __restrict__ se,
                                                 float* __restrict__ dout){
  __shared__ float ls[256*LPAD];
  int row0 = blockIdx.x*32;        // 2048 blocks
  int b  = row0 >> 10;
  int n0 = row0 & 1023;
  int o  = threadIdx.x;
  float acc[32];
  #pragma unroll
  for (int m=0;m<32;++m) acc[m]=0.f;
  for (int ch=0; ch<8; ++ch){
    int cc = ch*32;
    stage_w(ow + cc, 256, ls, o);
    __syncthreads();
    float wf[32];
    const float* wr = ls + o*LPAD;
    #pragma unroll
    for (int i=0;i<32;++i) wf[i] = wr[i];
    #pragma unroll
    for (int m=0;m<32;++m){
      const float* xrow = at + (row0+m)*CD + cc;   // wave-uniform
      #pragma unroll
      for (int i=0;i<32;++i) acc[m] += xrow[i]*wf[i];
    }
    __syncthreads();
  }
  float obo = obv[o];
  float sev = se[b*CD + o];
  #pragma unroll
  for (int m=0;m<32;++m){
    float val = (acc[m]+obo)*sev;
    dout[((n0+m)*NB + b)*CD + o] = val;
  }
}

extern "C" void kernel_launch(void* const* d_in, const int* in_sizes, int n_in,
                              void* d_out, int out_size, void* d_ws, size_t ws_size,
                              hipStream_t stream) {
  const float* query = (const float*)d_in[0];
  const float* ipw = (const float*)d_in[5];
  const float* ipb = (const float*)d_in[6];
  const float* srw = (const float*)d_in[7];
  const float* srb = (const float*)d_in[8];
  const float* ng  = (const float*)d_in[9];
  const float* nbb = (const float*)d_in[10];
  const float* ow  = (const float*)d_in[11];
  const float* obv = (const float*)d_in[12];
  const float* sw1 = (const float*)d_in[13];
  const float* sw2 = (const float*)d_in[14];
  float* dout = (float*)d_out;
  float* ws = (float*)d_ws;

  float* qbuf = ws;                 // 16,777,216 f
  float* at   = ws + 16777216;      // 16,777,216 f
  float* xr   = ws + 33554432;      //  4,194,304 f
  float* kb   = ws + 37748736;      //  4,194,304 f
  float* vb   = ws + 41943040;      //  4,194,304 f
  float* kv   = ws + 46137344;      //  2,097,152 f
  float* ks   = ws + 48234496;      //     65,536 f
  float* part = ws + 48300032;      //     65,536 f
  float* se   = ws + 48365568;      //     16,384 f
  float* t1   = ws + 48381952;      //      4,096 f
  float* t2   = ws + 48386048;      //      1,024 f

  k_trig  <<<4,    256,0,stream>>>(t1, t2);
  k_semean<<<256,  256,0,stream>>>(query, part);
  k_semlp <<<64,   256,0,stream>>>(part, sw1, sw2, se);
  k_conv  <<<512,  256,0,stream>>>(query, srw, srb, xr);
  k_ln    <<<4096, 256,0,stream>>>(xr, ng, nbb);
  k_kvproj<<<512,  256,0,stream>>>(xr, ipw, ipb, kb, vb);
  k_qproj <<<2048, 256,0,stream>>>(query, ipw, ipb, qbuf);
  k_kv    <<<512,  256,0,stream>>>(kb, vb, t2, kv, ks);
  k_attn  <<<512,  256,0,stream>>>(qbuf, kv, ks, t1, at);
  k_outproj<<<2048,256,0,stream>>>(at, ow, obv, se, dout);
}

// Round 4
// 743.652 us; speedup vs baseline: 3.7353x; 3.7353x over previous
//
#include <hip/hip_runtime.h>
#include <hip/hip_bf16.h>

#define NTOK 1024
#define NB   64
#define CD   256
#define NHEAD 8
#define HDIM 32
#define NS 256      // 16*16 reduced tokens
#define NBC  16384  // NB*CD
#define KC   32     // K-chunk
#define SA   132    // LDS row stride for 128-wide tiles (16B-aligned rows, pad 4)
#define SA64 68     // LDS row stride for 64-wide tiles

// ---- stage 128 rows x 32 cols, transposed into ls[k][r] (k=col, r=row) ----
// 8 consecutive threads read one 128B row segment (coalesced float4).
__device__ __forceinline__ void stage128(float* __restrict__ ls, const float* __restrict__ g0,
                                         int rstride, int t){
  #pragma unroll
  for (int rep=0;rep<4;++rep){
    int r = (t>>3) + rep*32;
    int f = t&7;
    float4 v = *(const float4*)(g0 + r*rstride + f*4);
    float* d = ls + (f*4)*SA + r;
    d[0]=v.x; d[SA]=v.y; d[2*SA]=v.z; d[3*SA]=v.w;
  }
}

// ---- 128x128 tile compute: 8x8 per thread ----
__device__ __forceinline__ void mm128(const float* __restrict__ As, const float* __restrict__ Bs,
                                      float (&acc)[8][8], int tm, int tn){
  #pragma unroll
  for (int k=0;k<KC;++k){
    float4 a0 = *(const float4*)(As + k*SA + tm*4);
    float4 a1 = *(const float4*)(As + k*SA + 64 + tm*4);
    float4 b0 = *(const float4*)(Bs + k*SA + tn*4);
    float4 b1 = *(const float4*)(Bs + k*SA + 64 + tn*4);
    float av[8] = {a0.x,a0.y,a0.z,a0.w,a1.x,a1.y,a1.z,a1.w};
    float bv[8] = {b0.x,b0.y,b0.z,b0.w,b1.x,b1.y,b1.z,b1.w};
    #pragma unroll
    for (int i=0;i<8;++i)
      #pragma unroll
      for (int j=0;j<8;++j) acc[i][j] += av[i]*bv[j];
  }
}

// ---- trig tables ----
__global__ __launch_bounds__(256) void k_trig(float* __restrict__ t1, float* __restrict__ t2){
  int n = blockIdx.x*256 + threadIdx.x;
  const float c = 1.57079632679489662f;
  float aa = c * (float)(n >> 5) / 32.0f;
  float bb = c * (float)(n & 31) / 32.0f;
  t1[n*4+0]=cosf(aa); t1[n*4+1]=sinf(aa); t1[n*4+2]=cosf(bb); t1[n*4+3]=sinf(bb);
  if (n < 256){
    float a2 = c * (float)(n >> 4) / 16.0f;
    float b2 = c * (float)(n & 15) / 16.0f;
    t2[n*4+0]=cosf(a2); t2[n*4+1]=sinf(a2); t2[n*4+2]=cosf(b2); t2[n*4+3]=sinf(b2);
  }
}

// ---- SE: partial mean ----
__global__ __launch_bounds__(256) void k_semean(const float* __restrict__ q, float* __restrict__ part){
  int b = blockIdx.x >> 2, qr = blockIdx.x & 3;
  int c = threadIdx.x;
  const float* qp = q + (qr*256)*NBC + b*CD + c;
  float s0=0.f,s1=0.f,s2=0.f,s3=0.f;
  for (int n=0;n<256;n+=4){
    s0 += qp[(n  )*NBC];
    s1 += qp[(n+1)*NBC];
    s2 += qp[(n+2)*NBC];
    s3 += qp[(n+3)*NBC];
  }
  part[blockIdx.x*256 + c] = (s0+s1)+(s2+s3);
}

// ---- SE MLP ----
__global__ __launch_bounds__(256) void k_semlp(const float* __restrict__ part, const float* __restrict__ w1,
                                               const float* __restrict__ w2, float* __restrict__ se){
  __shared__ float sm[256];
  __shared__ float s1s[128];
  int b = blockIdx.x, t = threadIdx.x;
  float s = (part[(b*4+0)*256+t]+part[(b*4+1)*256+t])+(part[(b*4+2)*256+t]+part[(b*4+3)*256+t]);
  sm[t] = s*(1.0f/1024.0f);
  __syncthreads();
  if (t < 128){
    float a = 0.f;
    const float* wr = w1 + t*256;
    for (int c=0;c<256;c+=4){
      float4 wf = *(const float4*)(wr+c);
      a += sm[c]*wf.x + sm[c+1]*wf.y + sm[c+2]*wf.z + sm[c+3]*wf.w;
    }
    s1s[t] = fmaxf(a, 0.f);
  }
  __syncthreads();
  float a = 0.f;
  const float* wr2 = w2 + t*128;
  for (int c=0;c<128;c+=4){
    float4 wf = *(const float4*)(wr2+c);
    a += s1s[c]*wf.x + s1s[c+1]*wf.y + s1s[c+2]*wf.z + s1s[c+3]*wf.w;
  }
  se[b*256+t] = 1.0f/(1.0f+expf(-a));
}

// ---- conv 2x2/s2 as tiled GEMM: M=16384 (64-tiles), N=256 (128-tiles), K'=1024 ----
__global__ __launch_bounds__(256) void k_conv(const float* __restrict__ query, const float* __restrict__ srw,
                                              const float* __restrict__ srb, float* __restrict__ xr){
  __shared__ float As[KC*SA64];
  __shared__ float Bs[KC*SA];
  int mt = blockIdx.x >> 1;            // 256 m-tiles of 64 positions
  int nt = blockIdx.x & 1;
  int m0 = mt*64;
  int b  = m0 >> 8, pos0 = m0 & 255;
  int n0 = nt*128;
  int t  = threadIdx.x;
  int tm = t & 15, tn = t >> 4;
  float acc[4][8] = {};
  const float* xb = query + b*CD;
  #pragma unroll
  for (int g=0; g<4; ++g){             // (kh,kw) group — compile-time after unroll
    int gh = g>>1, gw = g&1;
    for (int s=0; s<8; ++s){
      int cin0 = s*32;
      // stage A: 64 rows (positions) x 32 cins, transposed
      #pragma unroll
      for (int rep=0;rep<2;++rep){
        int r = (t>>3) + rep*32;
        int f = t&7;
        int pos = pos0 + r;
        int hs = pos>>4, ws = pos&15;
        int nn = (2*hs+gh)*32 + 2*ws + gw;
        float4 v = *(const float4*)(xb + nn*NBC + cin0 + f*4);
        float* d = As + (f*4)*SA64 + r;
        d[0]=v.x; d[SA64]=v.y; d[2*SA64]=v.z; d[3*SA64]=v.w;
      }
      // stage B: W[o][cin][kh][kw] -> Bs[cin_local][o_local]; pick comp g
      {
        int o = n0 + (t>>1);
        const float* rp = srw + o*1024 + cin0*4;
        int c0 = (t&1)*16;
        #pragma unroll
        for (int rep=0;rep<4;++rep){
          #pragma unroll
          for (int j=0;j<4;++j){
            int c = c0 + rep*4 + j;
            float4 v = *(const float4*)(rp + c*4);
            float val = (g==0)?v.x:((g==1)?v.y:((g==2)?v.z:v.w));
            Bs[c*SA + (t>>1)] = val;
          }
        }
      }
      __syncthreads();
      #pragma unroll
      for (int k=0;k<KC;++k){
        float4 a0 = *(const float4*)(As + k*SA64 + tm*4);
        float4 b0 = *(const float4*)(Bs + k*SA + tn*8);
        float4 b1 = *(const float4*)(Bs + k*SA + tn*8 + 4);
        float av[4] = {a0.x,a0.y,a0.z,a0.w};
        float bv[8] = {b0.x,b0.y,b0.z,b0.w,b1.x,b1.y,b1.z,b1.w};
        #pragma unroll
        for (int i=0;i<4;++i)
          #pragma unroll
          for (int j=0;j<8;++j) acc[i][j] += av[i]*bv[j];
      }
      __syncthreads();
    }
  }
  // epilogue: + bias, store
  #pragma unroll
  for (int jh=0;jh<2;++jh){
    int c = n0 + tn*8 + jh*4;
    float4 bias = *(const float4*)(srb + c);
    #pragma unroll
    for (int i=0;i<4;++i){
      int m = m0 + tm*4 + i;
      float4 v;
      v.x = acc[i][jh*4+0] + bias.x;
      v.y = acc[i][jh*4+1] + bias.y;
      v.z = acc[i][jh*4+2] + bias.z;
      v.w = acc[i][jh*4+3] + bias.w;
      *(float4*)(xr + m*CD + c) = v;
    }
  }
}

// ---- layernorm over C, in place ----
__global__ __launch_bounds__(256) void k_ln(float* __restrict__ xr, const float* __restrict__ g,
                                            const float* __restrict__ bta){
  int wv = threadIdx.x >> 6, lane = threadIdx.x & 63;
  int row = blockIdx.x*4 + wv;
  float4 v = ((const float4*)(xr + row*CD))[lane];
  float s = (v.x+v.y)+(v.z+v.w);
  #pragma unroll
  for (int off=1; off<64; off<<=1) s += __shfl_xor(s, off, 64);
  float mu = s * (1.0f/256.0f);
  float dx=v.x-mu, dy=v.y-mu, dz=v.z-mu, dw=v.w-mu;
  float s2 = (dx*dx+dy*dy)+(dz*dz+dw*dw);
  #pragma unroll
  for (int off=1; off<64; off<<=1) s2 += __shfl_xor(s2, off, 64);
  float inv = 1.0f / sqrtf(s2*(1.0f/256.0f) + 1e-5f);
  float4 gr = ((const float4*)g)[lane];
  float4 br = ((const float4*)bta)[lane];
  float4 o;
  o.x = dx*inv*gr.x + br.x;
  o.y = dy*inv*gr.y + br.y;
  o.z = dz*inv*gr.z + br.z;
  o.w = dw*inv*gr.w + br.w;
  ((float4*)(xr + row*CD))[lane] = o;
}

// ---- Q proj as tiled GEMM; writes qT[((b*8+h)*32+j)][ntok] (transposed) ----
__global__ __launch_bounds__(256) void k_qproj(const float* __restrict__ query, const float* __restrict__ ipw,
                                               const float* __restrict__ ipb, float* __restrict__ qT){
  __shared__ float As[KC*SA];
  __shared__ float Bs[KC*SA];
  int mt = blockIdx.x >> 1;            // 512 m-tiles of 128 tokens
  int nt = blockIdx.x & 1;
  int m0 = mt*128;
  int b  = m0 >> 10, ntok0 = m0 & 1023;
  int n0 = nt*128;
  int t  = threadIdx.x;
  int tm = t & 15, tn = t >> 4;
  float acc[8][8] = {};
  const float* Abase = query + (ntok0*NB + b)*CD;
  const float* Bbase = ipw + n0*CD;
  for (int kc=0; kc<CD; kc+=KC){
    stage128(As, Abase + kc, NBC, t);
    stage128(Bs, Bbase + kc, CD, t);
    __syncthreads();
    mm128(As, Bs, acc, tm, tn);
    __syncthreads();
  }
  const float sc = 0.17677669529663687f;
  #pragma unroll
  for (int jh=0;jh<2;++jh){
    #pragma unroll
    for (int jj=0;jj<4;++jj){
      int c = n0 + jh*64 + tn*4 + jj;
      float bias = ipb[c];
      int h = c>>5, jbit = c&31;
      float* dst = qT + ((b*8+h)*32 + jbit)*1024 + ntok0;
      #pragma unroll
      for (int ih=0; ih<2; ++ih){
        float4 v;
        v.x = fmaxf(acc[ih*4+0][jh*4+jj]+bias,0.f)*sc;
        v.y = fmaxf(acc[ih*4+1][jh*4+jj]+bias,0.f)*sc;
        v.z = fmaxf(acc[ih*4+2][jh*4+jj]+bias,0.f)*sc;
        v.w = fmaxf(acc[ih*4+3][jh*4+jj]+bias,0.f)*sc;
        *(float4*)(dst + ih*64 + tm*4) = v;
      }
    }
  }
}

// ---- K/V proj as one tiled GEMM over N=512 (K rows then V rows of in_proj) ----
__global__ __launch_bounds__(256) void k_kvproj(const float* __restrict__ xr, const float* __restrict__ ipw,
                                                const float* __restrict__ ipb, float* __restrict__ kb,
                                                float* __restrict__ vbuf){
  __shared__ float As[KC*SA];
  __shared__ float Bs[KC*SA];
  int mt = blockIdx.x >> 2;            // 128 m-tiles of 128 rows
  int nt = blockIdx.x & 3;             // 0,1 -> K ; 2,3 -> V
  int m0 = mt*128;
  int t  = threadIdx.x;
  int tm = t & 15, tn = t >> 4;
  float acc[8][8] = {};
  const float* Abase = xr + m0*CD;
  const float* Bbase = ipw + (256 + nt*128)*CD;
  for (int kc=0; kc<CD; kc+=KC){
    stage128(As, Abase + kc, CD, t);
    stage128(Bs, Bbase + kc, CD, t);
    __syncthreads();
    mm128(As, Bs, acc, tm, tn);
    __syncthreads();
  }
  #pragma unroll
  for (int ih=0;ih<2;++ih){
    #pragma unroll
    for (int i=0;i<4;++i){
      int m = m0 + ih*64 + tm*4 + i;
      #pragma unroll
      for (int jh=0;jh<2;++jh){
        int nl = jh*64 + tn*4;
        int nglob = nt*128 + nl;
        float4 v;
        v.x = acc[ih*4+i][jh*4+0];
        v.y = acc[ih*4+i][jh*4+1];
        v.z = acc[ih*4+i][jh*4+2];
        v.w = acc[ih*4+i][jh*4+3];
        if (nt < 2){
          float4 bias = *(const float4*)(ipb + 256 + nglob);
          v.x = fmaxf(v.x+bias.x, 0.f);
          v.y = fmaxf(v.y+bias.y, 0.f);
          v.z = fmaxf(v.z+bias.z, 0.f);
          v.w = fmaxf(v.w+bias.w, 0.f);
          *(float4*)(kb + m*CD + nglob) = v;
        } else {
          int nv = nglob - 256;
          float4 bias = *(const float4*)(ipb + 512 + nv);
          v.x += bias.x; v.y += bias.y; v.z += bias.z; v.w += bias.w;
          *(float4*)(vbuf + m*CD + nv) = v;
        }
      }
    }
  }
}

// ---- kv[bh][d=32p+j][m] = sum_n t2_p(n) k[n,j] v[n,m]; ksum[bh][d] ----
__global__ __launch_bounds__(256) void k_kv(const float* __restrict__ kb, const float* __restrict__ vbuf,
                                            const float* __restrict__ t2, float* __restrict__ kv,
                                            float* __restrict__ ksm){
  int bh = blockIdx.x; int b = bh >> 3, h = bh & 7;
  int t = threadIdx.x; int jq = t >> 5, m = t & 31;
  float acc[4][4];
  #pragma unroll
  for (int p=0;p<4;++p){ acc[p][0]=0.f; acc[p][1]=0.f; acc[p][2]=0.f; acc[p][3]=0.f; }
  const float* kbase = kb + h*HDIM + jq*4;
  const float* vbase = vbuf + h*HDIM + m;
  for (int n=0;n<256;++n){
    int ro = (b*NS + n)*CD;
    float4 k4 = *(const float4*)(kbase + ro);
    float vv = vbase[ro];
    float4 tt = *(const float4*)(t2 + n*4);
    float tv[4] = {tt.x, tt.y, tt.z, tt.w};
    float kk[4] = {k4.x, k4.y, k4.z, k4.w};
    #pragma unroll
    for (int p=0;p<4;++p){
      float tp = tv[p]*vv;
      #pragma unroll
      for (int jj=0;jj<4;++jj) acc[p][jj] += tp*kk[jj];
    }
  }
  #pragma unroll
  for (int p=0;p<4;++p){
    #pragma unroll
    for (int jj=0;jj<4;++jj)
      kv[bh*4096 + (p*32 + jq*4 + jj)*32 + m] = acc[p][jj];
  }
  if (t < 128){
    int p = t >> 5, j = t & 31;
    float s=0.f;
    const float* kp = kb + h*HDIM + j;
    for (int n=0;n<256;++n) s += t2[n*4+p]*kp[(b*NS+n)*CD];
    ksm[bh*128 + t] = s;
  }
}

// ---- attn: kv tile in LDS (broadcast reads), q from qT coalesced; 4 tokens/thread ----
__global__ __launch_bounds__(256, 2) void k_attn(const float* __restrict__ qT, const float* __restrict__ kv,
                                                 const float* __restrict__ ksm, const float* __restrict__ t1,
                                                 float* __restrict__ at){
  __shared__ float skv[128*32];
  __shared__ float sks[128];
  int bh = blockIdx.x, b = bh>>3, h = bh&7;
  int t = threadIdx.x;
  #pragma unroll
  for (int i=0;i<4;++i){
    int idx = i*256 + t;
    ((float4*)skv)[idx] = ((const float4*)(kv + bh*4096))[idx];
  }
  if (t < 128) sks[t] = ksm[bh*128 + t];
  __syncthreads();
  float acc[4][32] = {};
  float den[4] = {0.f,0.f,0.f,0.f};
  float4 tt[4];
  #pragma unroll
  for (int u=0;u<4;++u) tt[u] = *(const float4*)(t1 + (u*256+t)*4);
  const float* qcol = qT + (bh*32)*1024 + t;
  for (int j=0;j<32;++j){
    float qv[4];
    #pragma unroll
    for (int u=0;u<4;++u) qv[u] = qcol[j*1024 + u*256];
    #pragma unroll
    for (int p=0;p<4;++p){
      int d = p*32 + j;
      float kvr[32];
      #pragma unroll
      for (int q8=0;q8<8;++q8){
        float4 v = *(const float4*)(skv + d*32 + q8*4);
        kvr[q8*4]=v.x; kvr[q8*4+1]=v.y; kvr[q8*4+2]=v.z; kvr[q8*4+3]=v.w;
      }
      float ks = sks[d];
      #pragma unroll
      for (int u=0;u<4;++u){
        float tp = (p==0)?tt[u].x:((p==1)?tt[u].y:((p==2)?tt[u].z:tt[u].w));
        float tq = tp*qv[u];
        #pragma unroll
        for (int m=0;m<32;++m) acc[u][m] += tq*kvr[m];
        den[u] += tq*ks;
      }
    }
  }
  #pragma unroll
  for (int u=0;u<4;++u){
    float dn = den[u];
    float sgn = (dn>0.f) ? 1.f : ((dn<0.f)? -1.f : 0.f);
    float ad = fminf(fmaxf(fabsf(dn), 1e-4f), 1e4f);
    float inv = (dn != 0.f) ? 1.0f/(ad*sgn) : 0.f;
    int n = u*256 + t;
    float* outb = at + (b*NTOK + n)*CD + h*HDIM;
    #pragma unroll
    for (int mq=0;mq<8;++mq){
      float4 o4 = make_float4(acc[u][mq*4]*inv, acc[u][mq*4+1]*inv,
                              acc[u][mq*4+2]*inv, acc[u][mq*4+3]*inv);
      ((float4*)outb)[mq] = o4;
    }
  }
}

// ---- out proj as tiled GEMM + SE scale + transpose to (N,B,C) ----
__global__ __launch_bounds__(256) void k_outproj(const float* __restrict__ at, const float* __restrict__ ow,
                                                 const float* __restrict__ obv, const float* __restrict__ se,
                                                 float* __restrict__ dout){
  __shared__ float As[KC*SA];
  __shared__ float Bs[KC*SA];
  int mt = blockIdx.x >> 1;            // 512 m-tiles
  int nt = blockIdx.x & 1;
  int m0 = mt*128;
  int b  = m0 >> 10, ntok0 = m0 & 1023;
  int n0 = nt*128;
  int t  = threadIdx.x;
  int tm = t & 15, tn = t >> 4;
  float acc[8][8] = {};
  const float* Abase = at + m0*CD;
  const float* Bbase = ow + n0*CD;
  for (int kc=0; kc<CD; kc+=KC){
    stage128(As, Abase + kc, CD, t);
    stage128(Bs, Bbase + kc, CD, t);
    __syncthreads();
    mm128(As, Bs, acc, tm, tn);
    __syncthreads();
  }
  #pragma unroll
  for (int ih=0;ih<2;++ih){
    #pragma unroll
    for (int i=0;i<4;++i){
      int ntok = ntok0 + ih*64 + tm*4 + i;
      float* orow = dout + (ntok*NB + b)*CD;
      #pragma unroll
      for (int jh=0;jh<2;++jh){
        int c = n0 + jh*64 + tn*4;
        float4 bias = *(const float4*)(obv + c);
        float4 sev  = *(const float4*)(se + b*CD + c);
        float4 v;
        v.x = (acc[ih*4+i][jh*4+0]+bias.x)*sev.x;
        v.y = (acc[ih*4+i][jh*4+1]+bias.y)*sev.y;
        v.z = (acc[ih*4+i][jh*4+2]+bias.z)*sev.z;
        v.w = (acc[ih*4+i][jh*4+3]+bias.w)*sev.w;
        *(float4*)(orow + c) = v;
      }
    }
  }
}

extern "C" void kernel_launch(void* const* d_in, const int* in_sizes, int n_in,
                              void* d_out, int out_size, void* d_ws, size_t ws_size,
                              hipStream_t stream) {
  const float* query = (const float*)d_in[0];
  const float* ipw = (const float*)d_in[5];
  const float* ipb = (const float*)d_in[6];
  const float* srw = (const float*)d_in[7];
  const float* srb = (const float*)d_in[8];
  const float* ng  = (const float*)d_in[9];
  const float* nbb = (const float*)d_in[10];
  const float* ow  = (const float*)d_in[11];
  const float* obv = (const float*)d_in[12];
  const float* sw1 = (const float*)d_in[13];
  const float* sw2 = (const float*)d_in[14];
  float* dout = (float*)d_out;
  float* ws = (float*)d_ws;

  float* qT   = ws;                 // 16,777,216 f  (q transposed: [(b,h,j)][ntok])
  float* at   = ws + 16777216;      // 16,777,216 f  (attn, [b*1024+n][c])
  float* xr   = ws + 33554432;      //  4,194,304 f
  float* kb   = ws + 37748736;      //  4,194,304 f
  float* vb   = ws + 41943040;      //  4,194,304 f
  float* kv   = ws + 46137344;      //  2,097,152 f
  float* ks   = ws + 48234496;      //     65,536 f
  float* part = ws + 48300032;      //     65,536 f
  float* se   = ws + 48365568;      //     16,384 f
  float* t1   = ws + 48381952;      //      4,096 f
  float* t2   = ws + 48386048;      //      1,024 f

  k_trig  <<<4,    256,0,stream>>>(t1, t2);
  k_semean<<<256,  256,0,stream>>>(query, part);
  k_semlp <<<64,   256,0,stream>>>(part, sw1, sw2, se);
  k_conv  <<<512,  256,0,stream>>>(query, srw, srb, xr);
  k_ln    <<<4096, 256,0,stream>>>(xr, ng, nbb);
  k_kvproj<<<512,  256,0,stream>>>(xr, ipw, ipb, kb, vb);
  k_qproj <<<1024, 256,0,stream>>>(query, ipw, ipb, qT);
  k_kv    <<<512,  256,0,stream>>>(kb, vb, t2, kv, ks);
  k_attn  <<<512,  256,0,stream>>>(qT, kv, ks, t1, at);
  k_outproj<<<1024,256,0,stream>>>(at, ow, obv, se, dout);
}

// Round 5
// 506.310 us; speedup vs baseline: 5.4863x; 1.4688x over previous
//
#include <hip/hip_runtime.h>

#define NTOK 1024
#define NB   64
#define CD   256
#define NHEAD 8
#define HDIM 32
#define NS 256
#define NBC 16384

typedef __attribute__((ext_vector_type(8))) short short8v;
typedef __attribute__((ext_vector_type(4))) short short4v;
typedef __attribute__((ext_vector_type(4))) float f32x4;

// round-to-nearest-even fp32 -> bf16 (low 16 bits returned)
__device__ __forceinline__ unsigned bfr(float x){
  unsigned u = __float_as_uint(x);
  return (u + 0x7fffu + ((u>>16)&1u)) >> 16;
}
// two-term split: x ~= hi + lo, both bf16
__device__ __forceinline__ void split2(float x, short &h, short &l){
  unsigned hu = bfr(x);
  float hf = __uint_as_float(hu << 16);
  unsigned lu = bfr(x - hf);
  h = (short)hu; l = (short)lu;
}

// ---- weights -> bf16 hi/lo planes (row-major [n][k]) ----
// Wi: ipw 768x256 ; Wo: ow 256x256 ; Ws: srw reordered to [o][k'=g*256+cin] 256x1024
__global__ __launch_bounds__(256) void k_wcvt(const float* __restrict__ ipw, const float* __restrict__ ow,
                                              const float* __restrict__ srw,
                                              short* __restrict__ Wih, short* __restrict__ Wil,
                                              short* __restrict__ Woh, short* __restrict__ Wol,
                                              short* __restrict__ Wsh, short* __restrict__ Wsl){
  int u = blockIdx.x*256 + threadIdx.x;   // 65536 units of 8 elements
  float xs[8];
  short* dh; short* dl; int dof;
  if (u < 24576){
    int n = u >> 5, off = (u & 31)*8;
    const float* s = ipw + n*CD + off;
    #pragma unroll
    for (int i=0;i<8;++i) xs[i] = s[i];
    dh = Wih; dl = Wil; dof = n*CD + off;
  } else if (u < 32768){
    int v = u - 24576;
    int n = v >> 5, off = (v & 31)*8;
    const float* s = ow + n*CD + off;
    #pragma unroll
    for (int i=0;i<8;++i) xs[i] = s[i];
    dh = Woh; dl = Wol; dof = n*CD + off;
  } else {
    int v = u - 32768;
    int n = v >> 7, koff = (v & 127)*8;
    int g = koff >> 8, cin0 = koff & 255;
    #pragma unroll
    for (int i=0;i<8;++i) xs[i] = srw[n*1024 + (cin0+i)*4 + g];
    dh = Wsh; dl = Wsl; dof = n*1024 + koff;
  }
  short8v h, l;
  #pragma unroll
  for (int i=0;i<8;++i){ short a,b; split2(xs[i],a,b); h[i]=a; l[i]=b; }
  *(short8v*)(dh + dof) = h;
  *(short8v*)(dl + dof) = l;
}

// ---- query -> bf16 hi/lo planes, rows m = b*1024 + ntok ----
__global__ __launch_bounds__(256) void k_qcvt(const float* __restrict__ q, short* __restrict__ Qh,
                                              short* __restrict__ Ql){
  int idx = blockIdx.x*256 + threadIdx.x;      // 2,097,152 units of 8
  int m = idx >> 5;
  int off = (idx & 31)*8;
  const float* src = q + (m & 1023)*NBC + (m >> 10)*CD + off;
  float4 a = *(const float4*)src;
  float4 b4 = *(const float4*)(src+4);
  float xs[8] = {a.x,a.y,a.z,a.w,b4.x,b4.y,b4.z,b4.w};
  short8v h, l;
  #pragma unroll
  for (int i=0;i<8;++i){ short hh,ll; split2(xs[i],hh,ll); h[i]=hh; l[i]=ll; }
  *(short8v*)(Qh + m*CD + off) = h;
  *(short8v*)(Ql + m*CD + off) = l;
}

// ---- trig tables ----
__global__ __launch_bounds__(256) void k_trig(float* __restrict__ t1, float* __restrict__ t2){
  int n = blockIdx.x*256 + threadIdx.x;
  const float c = 1.57079632679489662f;
  float aa = c * (float)(n >> 5) / 32.0f;
  float bb = c * (float)(n & 31) / 32.0f;
  t1[n*4+0]=cosf(aa); t1[n*4+1]=sinf(aa); t1[n*4+2]=cosf(bb); t1[n*4+3]=sinf(bb);
  if (n < 256){
    float a2 = c * (float)(n >> 4) / 16.0f;
    float b2 = c * (float)(n & 15) / 16.0f;
    t2[n*4+0]=cosf(a2); t2[n*4+1]=sinf(a2); t2[n*4+2]=cosf(b2); t2[n*4+3]=sinf(b2);
  }
}

// ---- SE: partial mean ----
__global__ __launch_bounds__(256) void k_semean(const float* __restrict__ q, float* __restrict__ part){
  int b = blockIdx.x >> 2, qr = blockIdx.x & 3;
  int c = threadIdx.x;
  const float* qp = q + (qr*256)*NBC + b*CD + c;
  float s0=0.f,s1=0.f,s2=0.f,s3=0.f;
  for (int n=0;n<256;n+=4){
    s0 += qp[(n  )*NBC];
    s1 += qp[(n+1)*NBC];
    s2 += qp[(n+2)*NBC];
    s3 += qp[(n+3)*NBC];
  }
  part[blockIdx.x*256 + c] = (s0+s1)+(s2+s3);
}

// ---- SE MLP ----
__global__ __launch_bounds__(256) void k_semlp(const float* __restrict__ part, const float* __restrict__ w1,
                                               const float* __restrict__ w2, float* __restrict__ se){
  __shared__ float sm[256];
  __shared__ float s1s[128];
  int b = blockIdx.x, t = threadIdx.x;
  float s = (part[(b*4+0)*256+t]+part[(b*4+1)*256+t])+(part[(b*4+2)*256+t]+part[(b*4+3)*256+t]);
  sm[t] = s*(1.0f/1024.0f);
  __syncthreads();
  if (t < 128){
    float a = 0.f;
    const float* wr = w1 + t*256;
    for (int c=0;c<256;c+=4){
      float4 wf = *(const float4*)(wr+c);
      a += sm[c]*wf.x + sm[c+1]*wf.y + sm[c+2]*wf.z + sm[c+3]*wf.w;
    }
    s1s[t] = fmaxf(a, 0.f);
  }
  __syncthreads();
  float a = 0.f;
  const float* wr2 = w2 + t*128;
  for (int c=0;c<128;c+=4){
    float4 wf = *(const float4*)(wr2+c);
    a += s1s[c]*wf.x + s1s[c+1]*wf.y + s1s[c+2]*wf.z + s1s[c+3]*wf.w;
  }
  se[b*256+t] = 1.0f/(1.0f+expf(-a));
}

// ---- conv 2x2/s2 as MFMA GEMM: tile 64m x 128n, K'=1024 (k'=g*256+cin) ----
__global__ __launch_bounds__(256) void k_conv(const short* __restrict__ Qh, const short* __restrict__ Ql,
                                              const short* __restrict__ Wsh, const short* __restrict__ Wsl,
                                              const float* __restrict__ srb, float* __restrict__ xr){
  __shared__ __align__(16) short Ah[64*32];
  __shared__ __align__(16) short Al[64*32];
  __shared__ __align__(16) short Bh[128*32];
  __shared__ __align__(16) short Bl[128*32];
  int mblk = blockIdx.x >> 1, nblk = blockIdx.x & 1;
  int m0 = mblk*64, n0 = nblk*128;
  int b = mblk >> 2;
  int pos0 = m0 & 255;
  int t = threadIdx.x, wave = t>>6, lane = t&63;
  int wm = wave>>1, wn = wave&1;
  int q = lane>>4, r = lane&15;
  int ra = t>>2, pa = (t&3)*8;
  int posA = pos0 + ra, hs = posA>>4, ws2 = posA&15;
  const f32x4 fz = {0.f,0.f,0.f,0.f};
  f32x4 acc[2][4];
  #pragma unroll
  for (int s=0;s<2;++s)
    #pragma unroll
    for (int tt=0;tt<4;++tt) acc[s][tt] = fz;
  for (int kc=0; kc<32; ++kc){
    int g = kc>>3, cin0 = (kc&7)*32;
    int gh = g>>1, gw = g&1;
    int tok = (2*hs+gh)*32 + 2*ws2 + gw;
    int ga = ((b<<10) + tok)*CD + cin0 + pa;
    *(short8v*)(Ah + ra*32 + pa) = *(const short8v*)(Qh + ga);
    *(short8v*)(Al + ra*32 + pa) = *(const short8v*)(Ql + ga);
    int ko = kc*32;
    #pragma unroll
    for (int rep=0; rep<2; ++rep){
      int rr = ra + rep*64;
      int gb = (n0 + rr)*1024 + ko + pa;
      *(short8v*)(Bh + rr*32 + pa) = *(const short8v*)(Wsh + gb);
      *(short8v*)(Bl + rr*32 + pa) = *(const short8v*)(Wsl + gb);
    }
    __syncthreads();
    short8v ah[2], al[2];
    #pragma unroll
    for (int s=0;s<2;++s){
      int row = wm*32 + s*16 + r;
      ah[s] = *(const short8v*)(Ah + row*32 + q*8);
      al[s] = *(const short8v*)(Al + row*32 + q*8);
    }
    #pragma unroll
    for (int tt=0;tt<4;++tt){
      int brow = wn*64 + tt*16 + r;
      short8v bh = *(const short8v*)(Bh + brow*32 + q*8);
      short8v bl = *(const short8v*)(Bl + brow*32 + q*8);
      #pragma unroll
      for (int s=0;s<2;++s){
        acc[s][tt] = __builtin_amdgcn_mfma_f32_16x16x32_bf16(ah[s], bh, acc[s][tt], 0,0,0);
        acc[s][tt] = __builtin_amdgcn_mfma_f32_16x16x32_bf16(ah[s], bl, acc[s][tt], 0,0,0);
        acc[s][tt] = __builtin_amdgcn_mfma_f32_16x16x32_bf16(al[s], bh, acc[s][tt], 0,0,0);
      }
    }
    __syncthreads();
  }
  #pragma unroll
  for (int s=0;s<2;++s){
    #pragma unroll
    for (int tt=0;tt<4;++tt){
      int c = n0 + wn*64 + tt*16 + r;
      float bias = srb[c];
      #pragma unroll
      for (int i=0;i<4;++i){
        int m = m0 + wm*32 + s*16 + q*4 + i;
        xr[m*CD + c] = acc[s][tt][i] + bias;
      }
    }
  }
}

// ---- layernorm over C; reads xr fp32, writes bf16 hi/lo planes ----
__global__ __launch_bounds__(256) void k_ln(const float* __restrict__ xr, const float* __restrict__ g,
                                            const float* __restrict__ bta, short* __restrict__ Xh,
                                            short* __restrict__ Xl){
  int wv = threadIdx.x >> 6, lane = threadIdx.x & 63;
  int row = blockIdx.x*4 + wv;
  float4 v = ((const float4*)(xr + row*CD))[lane];
  float s = (v.x+v.y)+(v.z+v.w);
  #pragma unroll
  for (int off=1; off<64; off<<=1) s += __shfl_xor(s, off, 64);
  float mu = s * (1.0f/256.0f);
  float dx=v.x-mu, dy=v.y-mu, dz=v.z-mu, dw=v.w-mu;
  float s2 = (dx*dx+dy*dy)+(dz*dz+dw*dw);
  #pragma unroll
  for (int off=1; off<64; off<<=1) s2 += __shfl_xor(s2, off, 64);
  float inv = 1.0f / sqrtf(s2*(1.0f/256.0f) + 1e-5f);
  float4 gr = ((const float4*)g)[lane];
  float4 br = ((const float4*)bta)[lane];
  float o0 = dx*inv*gr.x + br.x;
  float o1 = dy*inv*gr.y + br.y;
  float o2 = dz*inv*gr.z + br.z;
  float o3 = dw*inv*gr.w + br.w;
  short4v h, l; short a0,b0;
  split2(o0,a0,b0); h[0]=a0; l[0]=b0;
  split2(o1,a0,b0); h[1]=a0; l[1]=b0;
  split2(o2,a0,b0); h[2]=a0; l[2]=b0;
  split2(o3,a0,b0); h[3]=a0; l[3]=b0;
  *(short4v*)(Xh + row*CD + lane*4) = h;
  *(short4v*)(Xl + row*CD + lane*4) = l;
}

// ---- Q proj MFMA: 128x128 tile, M=65536 (m=b*1024+ntok), N=256, K=256 ----
__global__ __launch_bounds__(256) void k_qproj(const short* __restrict__ Qh, const short* __restrict__ Ql,
                                               const short* __restrict__ Wih, const short* __restrict__ Wil,
                                               const float* __restrict__ ipb, float* __restrict__ qb){
  __shared__ __align__(16) short Ah[128*32];
  __shared__ __align__(16) short Al[128*32];
  __shared__ __align__(16) short Bh[128*32];
  __shared__ __align__(16) short Bl[128*32];
  int mblk = blockIdx.x >> 1, nblk = blockIdx.x & 1;
  int m0 = mblk*128, n0 = nblk*128;
  int t = threadIdx.x, wave = t>>6, lane = t&63;
  int wm = wave>>1, wn = wave&1;
  int q = lane>>4, r = lane&15;
  int cr = t>>2, cp = (t&3)*8;
  const f32x4 fz = {0.f,0.f,0.f,0.f};
  f32x4 acc[4][4];
  #pragma unroll
  for (int s=0;s<4;++s)
    #pragma unroll
    for (int tt=0;tt<4;++tt) acc[s][tt] = fz;
  for (int kc=0; kc<8; ++kc){
    int ko = kc*32;
    #pragma unroll
    for (int rep=0; rep<2; ++rep){
      int rr = cr + rep*64;
      int ga = (m0 + rr)*CD + ko + cp;
      *(short8v*)(Ah + rr*32 + cp) = *(const short8v*)(Qh + ga);
      *(short8v*)(Al + rr*32 + cp) = *(const short8v*)(Ql + ga);
      int gb = (n0 + rr)*CD + ko + cp;
      *(short8v*)(Bh + rr*32 + cp) = *(const short8v*)(Wih + gb);
      *(short8v*)(Bl + rr*32 + cp) = *(const short8v*)(Wil + gb);
    }
    __syncthreads();
    short8v ah[4], al[4];
    #pragma unroll
    for (int s=0;s<4;++s){
      int row = wm*64 + s*16 + r;
      ah[s] = *(const short8v*)(Ah + row*32 + q*8);
      al[s] = *(const short8v*)(Al + row*32 + q*8);
    }
    #pragma unroll
    for (int tt=0;tt<4;++tt){
      int brow = wn*64 + tt*16 + r;
      short8v bh = *(const short8v*)(Bh + brow*32 + q*8);
      short8v bl = *(const short8v*)(Bl + brow*32 + q*8);
      #pragma unroll
      for (int s=0;s<4;++s){
        acc[s][tt] = __builtin_amdgcn_mfma_f32_16x16x32_bf16(ah[s], bh, acc[s][tt], 0,0,0);
        acc[s][tt] = __builtin_amdgcn_mfma_f32_16x16x32_bf16(ah[s], bl, acc[s][tt], 0,0,0);
        acc[s][tt] = __builtin_amdgcn_mfma_f32_16x16x32_bf16(al[s], bh, acc[s][tt], 0,0,0);
      }
    }
    __syncthreads();
  }
  const float sc = 0.17677669529663687f;
  #pragma unroll
  for (int s=0;s<4;++s){
    #pragma unroll
    for (int tt=0;tt<4;++tt){
      int c = n0 + wn*64 + tt*16 + r;
      float bias = ipb[c];
      #pragma unroll
      for (int i=0;i<4;++i){
        int m = m0 + wm*64 + s*16 + q*4 + i;
        qb[m*CD + c] = fmaxf(acc[s][tt][i] + bias, 0.f)*sc;
      }
    }
  }
}

// ---- K/V proj MFMA: A = X planes (16384x256), B = ipw rows 256..767, N=512 ----
__global__ __launch_bounds__(256) void k_kvproj(const short* __restrict__ Xh, const short* __restrict__ Xl,
                                                const short* __restrict__ Wkh, const short* __restrict__ Wkl,
                                                const float* __restrict__ ipb, float* __restrict__ kb,
                                                float* __restrict__ vb){
  __shared__ __align__(16) short Ah[128*32];
  __shared__ __align__(16) short Al[128*32];
  __shared__ __align__(16) short Bh[128*32];
  __shared__ __align__(16) short Bl[128*32];
  int mblk = blockIdx.x >> 2, nblk = blockIdx.x & 3;
  int m0 = mblk*128, n0 = nblk*128;
  int t = threadIdx.x, wave = t>>6, lane = t&63;
  int wm = wave>>1, wn = wave&1;
  int q = lane>>4, r = lane&15;
  int cr = t>>2, cp = (t&3)*8;
  const f32x4 fz = {0.f,0.f,0.f,0.f};
  f32x4 acc[4][4];
  #pragma unroll
  for (int s=0;s<4;++s)
    #pragma unroll
    for (int tt=0;tt<4;++tt) acc[s][tt] = fz;
  for (int kc=0; kc<8; ++kc){
    int ko = kc*32;
    #pragma unroll
    for (int rep=0; rep<2; ++rep){
      int rr = cr + rep*64;
      int ga = (m0 + rr)*CD + ko + cp;
      *(short8v*)(Ah + rr*32 + cp) = *(const short8v*)(Xh + ga);
      *(short8v*)(Al + rr*32 + cp) = *(const short8v*)(Xl + ga);
      int gb = (n0 + rr)*CD + ko + cp;
      *(short8v*)(Bh + rr*32 + cp) = *(const short8v*)(Wkh + gb);
      *(short8v*)(Bl + rr*32 + cp) = *(const short8v*)(Wkl + gb);
    }
    __syncthreads();
    short8v ah[4], al[4];
    #pragma unroll
    for (int s=0;s<4;++s){
      int row = wm*64 + s*16 + r;
      ah[s] = *(const short8v*)(Ah + row*32 + q*8);
      al[s] = *(const short8v*)(Al + row*32 + q*8);
    }
    #pragma unroll
    for (int tt=0;tt<4;++tt){
      int brow = wn*64 + tt*16 + r;
      short8v bh = *(const short8v*)(Bh + brow*32 + q*8);
      short8v bl = *(const short8v*)(Bl + brow*32 + q*8);
      #pragma unroll
      for (int s=0;s<4;++s){
        acc[s][tt] = __builtin_amdgcn_mfma_f32_16x16x32_bf16(ah[s], bh, acc[s][tt], 0,0,0);
        acc[s][tt] = __builtin_amdgcn_mfma_f32_16x16x32_bf16(ah[s], bl, acc[s][tt], 0,0,0);
        acc[s][tt] = __builtin_amdgcn_mfma_f32_16x16x32_bf16(al[s], bh, acc[s][tt], 0,0,0);
      }
    }
    __syncthreads();
  }
  #pragma unroll
  for (int s=0;s<4;++s){
    #pragma unroll
    for (int tt=0;tt<4;++tt){
      int c = n0 + wn*64 + tt*16 + r;       // 0..511
      float bias = ipb[256 + c];
      #pragma unroll
      for (int i=0;i<4;++i){
        int m = m0 + wm*64 + s*16 + q*4 + i;
        float v = acc[s][tt][i] + bias;
        if (c < 256) kb[m*CD + c] = fmaxf(v, 0.f);
        else         vb[m*CD + (c-256)] = v;
      }
    }
  }
}

// ---- kv[bh][d][m], ksum[bh][d] (unchanged) ----
__global__ __launch_bounds__(256) void k_kv(const float* __restrict__ kb, const float* __restrict__ vbuf,
                                            const float* __restrict__ t2, float* __restrict__ kv,
                                            float* __restrict__ ksm){
  int bh = blockIdx.x; int b = bh >> 3, h = bh & 7;
  int t = threadIdx.x; int jq = t >> 5, m = t & 31;
  float acc[4][4];
  #pragma unroll
  for (int p=0;p<4;++p){ acc[p][0]=0.f; acc[p][1]=0.f; acc[p][2]=0.f; acc[p][3]=0.f; }
  const float* kbase = kb + h*HDIM + jq*4;
  const float* vbase = vbuf + h*HDIM + m;
  for (int n=0;n<256;++n){
    int ro = (b*NS + n)*CD;
    float4 k4 = *(const float4*)(kbase + ro);
    float vv = vbase[ro];
    float4 tt = *(const float4*)(t2 + n*4);
    float tv[4] = {tt.x, tt.y, tt.z, tt.w};
    float kk[4] = {k4.x, k4.y, k4.z, k4.w};
    #pragma unroll
    for (int p=0;p<4;++p){
      float tp = tv[p]*vv;
      #pragma unroll
      for (int jj=0;jj<4;++jj) acc[p][jj] += tp*kk[jj];
    }
  }
  #pragma unroll
  for (int p=0;p<4;++p){
    #pragma unroll
    for (int jj=0;jj<4;++jj)
      kv[bh*4096 + (p*32 + jq*4 + jj)*32 + m] = acc[p][jj];
  }
  if (t < 128){
    int p = t >> 5, j = t & 31;
    float s=0.f;
    const float* kp = kb + h*HDIM + j;
    for (int n=0;n<256;++n) s += t2[n*4+p]*kp[(b*NS+n)*CD];
    ksm[bh*128 + t] = s;
  }
}

// ---- attn: q staged via LDS from qb row-major; writes At hi/lo bf16 planes ----
__global__ __launch_bounds__(256) void k_attn(const float* __restrict__ qb, const float* __restrict__ kv,
                                              const float* __restrict__ ksm, const float* __restrict__ t1,
                                              short* __restrict__ Ath, short* __restrict__ Atl){
  __shared__ float skv[128*32];
  __shared__ float sks[128];
  __shared__ float sq[256*33];
  int bh = blockIdx.x, b = bh>>3, h = bh&7;
  int t = threadIdx.x;
  #pragma unroll
  for (int i=0;i<4;++i)
    ((float4*)skv)[i*256+t] = ((const float4*)(kv + bh*4096))[i*256+t];
  if (t < 128) sks[t] = ksm[bh*128 + t];
  for (int u=0;u<4;++u){
    __syncthreads();
    #pragma unroll
    for (int rep=0;rep<8;++rep){
      int rr = (t>>3) + rep*32;
      int f = t&7;
      float4 v = *(const float4*)(qb + (b*NTOK + u*256 + rr)*CD + h*HDIM + f*4);
      float* d = sq + rr*33 + f*4;
      d[0]=v.x; d[1]=v.y; d[2]=v.z; d[3]=v.w;
    }
    __syncthreads();
    int n = u*256 + t;
    float qf[32];
    #pragma unroll
    for (int i=0;i<32;++i) qf[i] = sq[t*33 + i];
    float4 tt = *(const float4*)(t1 + n*4);
    float tv[4] = {tt.x,tt.y,tt.z,tt.w};
    float acc[32];
    #pragma unroll
    for (int mm=0;mm<32;++mm) acc[mm]=0.f;
    float den = 0.f;
    #pragma unroll
    for (int p=0;p<4;++p){
      float tp = tv[p];
      for (int j=0;j<32;++j){
        float qq = tp*qf[j];
        const float* kvr = skv + (p*32+j)*32;
        float ks = sks[p*32+j];
        #pragma unroll
        for (int mm=0;mm<32;++mm) acc[mm] += qq*kvr[mm];
        den += qq*ks;
      }
    }
    float sgn = (den>0.f) ? 1.f : ((den<0.f)? -1.f : 0.f);
    float ad = fminf(fmaxf(fabsf(den), 1e-4f), 1e4f);
    float inv = (den != 0.f) ? 1.0f/(ad*sgn) : 0.f;
    int mrow = b*NTOK + n;
    #pragma unroll
    for (int mq=0;mq<4;++mq){
      short8v hh, ll;
      #pragma unroll
      for (int j=0;j<8;++j){
        short a0,b0; split2(acc[mq*8+j]*inv, a0, b0);
        hh[j]=a0; ll[j]=b0;
      }
      *(short8v*)(Ath + mrow*CD + h*HDIM + mq*8) = hh;
      *(short8v*)(Atl + mrow*CD + h*HDIM + mq*8) = ll;
    }
  }
}

// ---- out proj MFMA: A = At planes, B = ow planes; +bias, *se, transpose store ----
__global__ __launch_bounds__(256) void k_outproj(const short* __restrict__ Ath, const short* __restrict__ Atl,
                                                 const short* __restrict__ Woh, const short* __restrict__ Wol,
                                                 const float* __restrict__ obv, const float* __restrict__ se,
                                                 float* __restrict__ dout){
  __shared__ __align__(16) short Ah[128*32];
  __shared__ __align__(16) short Al[128*32];
  __shared__ __align__(16) short Bh[128*32];
  __shared__ __align__(16) short Bl[128*32];
  int mblk = blockIdx.x >> 1, nblk = blockIdx.x & 1;
  int m0 = mblk*128, n0 = nblk*128;
  int t = threadIdx.x, wave = t>>6, lane = t&63;
  int wm = wave>>1, wn = wave&1;
  int q = lane>>4, r = lane&15;
  int cr = t>>2, cp = (t&3)*8;
  const f32x4 fz = {0.f,0.f,0.f,0.f};
  f32x4 acc[4][4];
  #pragma unroll
  for (int s=0;s<4;++s)
    #pragma unroll
    for (int tt=0;tt<4;++tt) acc[s][tt] = fz;
  for (int kc=0; kc<8; ++kc){
    int ko = kc*32;
    #pragma unroll
    for (int rep=0; rep<2; ++rep){
      int rr = cr + rep*64;
      int ga = (m0 + rr)*CD + ko + cp;
      *(short8v*)(Ah + rr*32 + cp) = *(const short8v*)(Ath + ga);
      *(short8v*)(Al + rr*32 + cp) = *(const short8v*)(Atl + ga);
      int gb = (n0 + rr)*CD + ko + cp;
      *(short8v*)(Bh + rr*32 + cp) = *(const short8v*)(Woh + gb);
      *(short8v*)(Bl + rr*32 + cp) = *(const short8v*)(Wol + gb);
    }
    __syncthreads();
    short8v ah[4], al[4];
    #pragma unroll
    for (int s=0;s<4;++s){
      int row = wm*64 + s*16 + r;
      ah[s] = *(const short8v*)(Ah + row*32 + q*8);
      al[s] = *(const short8v*)(Al + row*32 + q*8);
    }
    #pragma unroll
    for (int tt=0;tt<4;++tt){
      int brow = wn*64 + tt*16 + r;
      short8v bh = *(const short8v*)(Bh + brow*32 + q*8);
      short8v bl = *(const short8v*)(Bl + brow*32 + q*8);
      #pragma unroll
      for (int s=0;s<4;++s){
        acc[s][tt] = __builtin_amdgcn_mfma_f32_16x16x32_bf16(ah[s], bh, acc[s][tt], 0,0,0);
        acc[s][tt] = __builtin_amdgcn_mfma_f32_16x16x32_bf16(ah[s], bl, acc[s][tt], 0,0,0);
        acc[s][tt] = __builtin_amdgcn_mfma_f32_16x16x32_bf16(al[s], bh, acc[s][tt], 0,0,0);
      }
    }
    __syncthreads();
  }
  #pragma unroll
  for (int s=0;s<4;++s){
    #pragma unroll
    for (int tt=0;tt<4;++tt){
      int c = n0 + wn*64 + tt*16 + r;
      float bias = obv[c];
      #pragma unroll
      for (int i=0;i<4;++i){
        int m = m0 + wm*64 + s*16 + q*4 + i;
        int bb = m >> 10, ntok = m & 1023;
        float sev = se[bb*CD + c];
        dout[(ntok*NB + bb)*CD + c] = (acc[s][tt][i] + bias)*sev;
      }
    }
  }
}

extern "C" void kernel_launch(void* const* d_in, const int* in_sizes, int n_in,
                              void* d_out, int out_size, void* d_ws, size_t ws_size,
                              hipStream_t stream) {
  const float* query = (const float*)d_in[0];
  const float* ipw = (const float*)d_in[5];
  const float* ipb = (const float*)d_in[6];
  const float* srw = (const float*)d_in[7];
  const float* srb = (const float*)d_in[8];
  const float* ng  = (const float*)d_in[9];
  const float* nbb = (const float*)d_in[10];
  const float* ow  = (const float*)d_in[11];
  const float* obv = (const float*)d_in[12];
  const float* sw1 = (const float*)d_in[13];
  const float* sw2 = (const float*)d_in[14];
  float* dout = (float*)d_out;
  float* ws = (float*)d_ws;

  // ---- workspace layout (float offsets; fits in < 45M floats, well under proven 48.4M) ----
  float* qb   = ws;                        // 16,777,216 f  [qproj -> attn]
  float* R1   = ws + 16777216;             // 16,777,216 f  multi-use region
  short* Qh   = (short*)R1;                //  Q hi plane (16.7M shorts)  [qcvt -> qproj]
  short* Ql   = (short*)(R1 + 8388608);    //  Q lo plane                 [qcvt -> qproj]
  float* kb   = R1;                        //  4,194,304 f  [kvproj -> k_kv]  (after Q planes dead)
  float* vb   = R1 + 4194304;              //  4,194,304 f  [kvproj -> k_kv]
  short* Ath  = (short*)R1;                //  At hi plane [attn -> outproj] (after kb/vb dead)
  short* Atl  = (short*)(R1 + 8388608);    //  At lo plane
  float* xr   = ws + 33554432;             //  4,194,304 f  [conv -> ln]
  short* Xh   = (short*)(ws + 37748736);   //  [ln -> kvproj]
  short* Xl   = (short*)(ws + 39845888);
  float* kv   = ws + 41943040;             //  2,097,152 f
  float* ks   = ws + 44040192;             //     65,536 f
  float* part = ws + 44105728;             //     65,536 f
  float* se   = ws + 44171264;             //     16,384 f
  float* t1   = ws + 44187648;             //      4,096 f
  float* t2   = ws + 44191744;             //      1,024 f
  short* Wih  = (short*)(ws + 44192768);   // 768x256
  short* Wil  = (short*)(ws + 44291072);
  short* Woh  = (short*)(ws + 44389376);   // 256x256
  short* Wol  = (short*)(ws + 44422144);
  short* Wsh  = (short*)(ws + 44454912);   // 256x1024
  short* Wsl  = (short*)(ws + 44585984);   // end: 44,717,056 f

  k_wcvt  <<<256,  256,0,stream>>>(ipw, ow, srw, Wih, Wil, Woh, Wol, Wsh, Wsl);
  k_qcvt  <<<8192, 256,0,stream>>>(query, Qh, Ql);
  k_trig  <<<4,    256,0,stream>>>(t1, t2);
  k_semean<<<256,  256,0,stream>>>(query, part);
  k_semlp <<<64,   256,0,stream>>>(part, sw1, sw2, se);
  k_conv  <<<512,  256,0,stream>>>(Qh, Ql, Wsh, Wsl, srb, xr);
  k_ln    <<<4096, 256,0,stream>>>(xr, ng, nbb, Xh, Xl);
  k_qproj <<<1024, 256,0,stream>>>(Qh, Ql, Wih, Wil, ipb, qb);       // before kvproj (kb/vb overlay Q planes)
  k_kvproj<<<512,  256,0,stream>>>(Xh, Xl, Wih + 256*CD, Wil + 256*CD, ipb, kb, vb);
  k_kv    <<<512,  256,0,stream>>>(kb, vb, t2, kv, ks);
  k_attn  <<<512,  256,0,stream>>>(qb, kv, ks, t1, Ath, Atl);
  k_outproj<<<1024,256,0,stream>>>(Ath, Atl, Woh, Wol, obv, se, dout);
}